// Round 1
// baseline (5086.789 us; speedup 1.0000x reference)
//
#include <hip/hip_runtime.h>
#include <cstdint>

// Problem constants
#define B_  16
#define T_  512
#define H_  1024
#define E_  1024
#define V_  32000

// MFMA fragment types (gfx950 v_mfma_f32_16x16x32_bf16: A/B = 8 x bf16, C/D = 4 x f32)
typedef __attribute__((ext_vector_type(8))) __bf16 frag8;
typedef __attribute__((ext_vector_type(4))) float  f32x4;
typedef unsigned short u16;

__device__ __forceinline__ f32x4 mfma16(frag8 a, frag8 b, f32x4 c) {
  return __builtin_amdgcn_mfma_f32_16x16x32_bf16(a, b, c, 0, 0, 0);
}

__device__ __forceinline__ u16 f2bf(float f) {  // fp32 -> bf16 RNE
  uint32_t u = __float_as_uint(f);
  u += 0x7fffu + ((u >> 16) & 1u);
  return (u16)(u >> 16);
}

// ---------------- fp32 -> bf16 convert, 4 elems/thread ----------------
__global__ __launch_bounds__(256) void k_convert(const float* __restrict__ src,
                                                 u16* __restrict__ dst, int n4) {
  int i = blockIdx.x * 256 + threadIdx.x;
  if (i >= n4) return;
  float4 v = ((const float4*)src)[i];
  ushort4 o;
  o.x = f2bf(v.x); o.y = f2bf(v.y); o.z = f2bf(v.z); o.w = f2bf(v.w);
  ((ushort4*)dst)[i] = o;
}

// ---------------- embedding gather + cast: one block per token ----------------
__global__ __launch_bounds__(256) void k_gather(const int* __restrict__ ids,
                                                const float* __restrict__ emb,
                                                u16* __restrict__ x) {
  int token = blockIdx.x;                    // b*T + t
  int id = ids[token];
  const float4* src = (const float4*)(emb + (size_t)id * E_);
  float4 v = src[threadIdx.x];               // 256 threads * 4 = 1024 elems
  ushort4 o;
  o.x = f2bf(v.x); o.y = f2bf(v.y); o.z = f2bf(v.z); o.w = f2bf(v.w);
  ((ushort4*)(x + (size_t)token * E_))[threadIdx.x] = o;
}

// ---------------- bf16 MFMA GEMM, C[M,N] = A[M,K] * Bm[N,K]^T + bias ----------------
// 128x128 tile, BK=32, 256 threads (4 waves, 2x2 of 64x64), m93-style staging.
__global__ __launch_bounds__(256) void k_gemm_bt(
    const u16* __restrict__ A, const u16* __restrict__ Bm, float* __restrict__ C,
    const float* __restrict__ bias0, const float* __restrict__ bias1,
    int N, int K) {
  __shared__ alignas(16) u16 As[128 * 32];
  __shared__ alignas(16) u16 Bs[128 * 32];
  const int tid  = threadIdx.x;
  const int wave = tid >> 6, lane = tid & 63;
  const int quad = lane >> 4, l16 = lane & 15;
  const int wm = (wave >> 1) * 64, wn = (wave & 1) * 64;
  const size_t am0 = (size_t)blockIdx.y * 128;
  const size_t bn0 = (size_t)blockIdx.x * 128;
  // staging map: thread covers rows (tid>>2) and (tid>>2)+64, 16B chunk (tid&3)
  const int r0 = tid >> 2, c0 = (tid & 3) * 8;
  f32x4 acc[4][4] = {};
  for (int k0 = 0; k0 < K; k0 += 32) {
    uint4 a0 = *(const uint4*)(A + (am0 + r0) * K + k0 + c0);
    uint4 a1 = *(const uint4*)(A + (am0 + 64 + r0) * K + k0 + c0);
    uint4 b0 = *(const uint4*)(Bm + (bn0 + r0) * K + k0 + c0);
    uint4 b1 = *(const uint4*)(Bm + (bn0 + 64 + r0) * K + k0 + c0);
    __syncthreads();                       // prior iteration finished reading LDS
    ((uint4*)As)[tid]       = a0;
    ((uint4*)As)[256 + tid] = a1;
    ((uint4*)Bs)[tid]       = b0;
    ((uint4*)Bs)[256 + tid] = b1;
    __syncthreads();
    frag8 af[4], bfv[4];
    for (int i = 0; i < 4; ++i)
      af[i] = *(const frag8*)&As[(wm + i * 16 + l16) * 32 + quad * 8];
    for (int j = 0; j < 4; ++j)
      bfv[j] = *(const frag8*)&Bs[(wn + j * 16 + l16) * 32 + quad * 8];
    for (int i = 0; i < 4; ++i)
      for (int j = 0; j < 4; ++j)
        acc[i][j] = mfma16(af[i], bfv[j], acc[i][j]);
    __syncthreads();
  }
  // epilogue: D row = quad*4+r (M-dim), col = l16 (N-dim)  [m89-verified mapping]
  for (int j = 0; j < 4; ++j) {
    int col = (int)bn0 + wn + j * 16 + l16;
    float bb = bias0 ? bias0[col] : 0.0f;
    if (bias1) bb += bias1[col];
    for (int i = 0; i < 4; ++i) {
      int row0 = (int)am0 + wm + i * 16 + quad * 4;
      for (int r = 0; r < 4; ++r)
        C[(size_t)(row0 + r) * N + col] = acc[i][j][r] + bb;
    }
  }
}

// ---------------- fused RNN step (one launch per t; layers pipelined) ----------------
// blocks 0..63  : layer 0, step t   (active when t < 512)
//   h0_t[b][j] = tanh(pre0[b][t][j] + sum_i h0_{t-1}[b][i]*Whh0[j][i])
// blocks 64..127: layer 1, step t-1 (active when t >= 1)
//   h1_tau[b][j] = tanh(bih1[j]+bhh1[j] + sum y0[b][tau]*Wih1[j] + sum h1_{tau-1}[b]*Whh1[j])
// MFMA M=batch(16), each WG owns one 16-wide N-tile; 4 waves split K, LDS reduce.
__global__ __launch_bounds__(256) void k_rnn_step(
    int t,
    const float* __restrict__ pre0,
    const u16* __restrict__ Whh0,
    const u16* __restrict__ Wih1, const u16* __restrict__ Whh1,
    const float* __restrict__ bih1, const float* __restrict__ bhh1,
    u16* __restrict__ y0, u16* __restrict__ y1,
    float* __restrict__ hid) {
  const int g = blockIdx.x;
  const bool grpA = (g < 64);
  const int ntile = grpA ? g : g - 64;
  const int tid = threadIdx.x;
  const int wave = tid >> 6, lane = tid & 63;
  const int quad = lane >> 4, l16 = lane & 15;
  __shared__ alignas(16) float part[1024];   // [wave][lane][reg]

  if (grpA) {
    if (t >= T_) return;
    f32x4 acc = {0.f, 0.f, 0.f, 0.f};
    if (t > 0) {
      const u16* hprev = y0 + (size_t)(t - 1) * H_;             // + b*T*H
      const u16* wrow  = Whh0 + (size_t)(ntile * 16 + l16) * H_; // n = j
      for (int kk = 0; kk < 8; ++kk) {
        int k = wave * 256 + kk * 32 + quad * 8;
        frag8 a = *(const frag8*)(hprev + (size_t)l16 * T_ * H_ + k);
        frag8 b = *(const frag8*)(wrow + k);
        acc = mfma16(a, b, acc);
      }
    }
    ((f32x4*)part)[wave * 64 + lane] = acc;
    __syncthreads();
    int m = tid >> 4, col = tid & 15;        // m = batch, col within n-tile
    int j = ntile * 16 + col;
    int li = (((m >> 2) * 16 + col) << 2) + (m & 3);
    float v = part[li] + part[256 + li] + part[512 + li] + part[768 + li];
    v += pre0[(size_t)m * T_ * H_ + (size_t)t * H_ + j];
    float h = tanhf(v);
    y0[(size_t)m * T_ * H_ + (size_t)t * H_ + j] = f2bf(h);
    if (t == T_ - 1) hid[(size_t)m * H_ + j] = h;
  } else {
    if (t < 1) return;
    const int tau = t - 1;
    f32x4 acc = {0.f, 0.f, 0.f, 0.f};
    const u16* wih = Wih1 + (size_t)(ntile * 16 + l16) * H_;
    const u16* xin = y0 + (size_t)tau * H_;
    for (int kk = 0; kk < 8; ++kk) {
      int k = wave * 256 + kk * 32 + quad * 8;
      frag8 a = *(const frag8*)(xin + (size_t)l16 * T_ * H_ + k);
      frag8 b = *(const frag8*)(wih + k);
      acc = mfma16(a, b, acc);
    }
    if (tau > 0) {
      const u16* whh = Whh1 + (size_t)(ntile * 16 + l16) * H_;
      const u16* hp  = y1 + (size_t)(tau - 1) * H_;
      for (int kk = 0; kk < 8; ++kk) {
        int k = wave * 256 + kk * 32 + quad * 8;
        frag8 a = *(const frag8*)(hp + (size_t)l16 * T_ * H_ + k);
        frag8 b = *(const frag8*)(whh + k);
        acc = mfma16(a, b, acc);
      }
    }
    ((f32x4*)part)[wave * 64 + lane] = acc;
    __syncthreads();
    int m = tid >> 4, col = tid & 15;
    int j = ntile * 16 + col;
    int li = (((m >> 2) * 16 + col) << 2) + (m & 3);
    float v = part[li] + part[256 + li] + part[512 + li] + part[768 + li];
    v += bih1[j] + bhh1[j];
    float h = tanhf(v);
    y1[(size_t)m * T_ * H_ + (size_t)tau * H_ + j] = f2bf(h);
    if (tau == T_ - 1) hid[(size_t)(B_ * H_) + (size_t)m * H_ + j] = h;
  }
}

extern "C" void kernel_launch(void* const* d_in, const int* in_sizes, int n_in,
                              void* d_out, int out_size, void* d_ws, size_t ws_size,
                              hipStream_t stream) {
  const int*   ids  = (const int*)d_in[0];
  const float* emb  = (const float*)d_in[1];
  const float* Wih0 = (const float*)d_in[2];
  const float* Whh0 = (const float*)d_in[3];
  const float* bih0 = (const float*)d_in[4];
  const float* bhh0 = (const float*)d_in[5];
  const float* Wih1 = (const float*)d_in[6];
  const float* Whh1 = (const float*)d_in[7];
  const float* bih1 = (const float*)d_in[8];
  const float* bhh1 = (const float*)d_in[9];
  const float* fcw  = (const float*)d_in[10];
  const float* fcb  = (const float*)d_in[11];
  float* out = (float*)d_out;
  char*  ws  = (char*)d_ws;

  // workspace layout (bytes), all offsets 256-aligned; total ~158 MB
  u16*   x_bf    = (u16*)(ws + 0);            // 16,777,216  [8192,1024] bf16
  u16*   wih0_bf = (u16*)(ws + 16777216);     //  2,097,152
  u16*   whh0_bf = (u16*)(ws + 18874368);     //  2,097,152
  u16*   wih1_bf = (u16*)(ws + 20971520);     //  2,097,152
  u16*   whh1_bf = (u16*)(ws + 23068672);     //  2,097,152
  u16*   fcw_bf  = (u16*)(ws + 25165824);     // 65,536,000  [32000,1024] bf16
  float* pre0    = (float*)(ws + 90701824);   // 33,554,432  [8192,1024] f32
  u16*   y0      = (u16*)(ws + 124256256);    // 16,777,216  [16,512,1024] bf16
  u16*   y1      = (u16*)(ws + 141033472);    // 16,777,216
  float* hid     = out + (size_t)B_ * T_ * V_; // [2,16,1024] f32 tail of d_out

  // 1) weight conversions to bf16
  k_convert<<<1024, 256, 0, stream>>>(Wih0, wih0_bf, H_ * H_ / 4);
  k_convert<<<1024, 256, 0, stream>>>(Whh0, whh0_bf, H_ * H_ / 4);
  k_convert<<<1024, 256, 0, stream>>>(Wih1, wih1_bf, H_ * H_ / 4);
  k_convert<<<1024, 256, 0, stream>>>(Whh1, whh1_bf, H_ * H_ / 4);
  k_convert<<<32000, 256, 0, stream>>>(fcw, fcw_bf, V_ * H_ / 4);

  // 2) embedding gather + cast
  k_gather<<<B_ * T_, 256, 0, stream>>>(ids, emb, x_bf);

  // 3) pre0 = x @ Wih0^T + bih0 + bhh0   [8192,1024]
  dim3 g1(H_ / 128, (B_ * T_) / 128);
  k_gemm_bt<<<g1, 256, 0, stream>>>(x_bf, wih0_bf, pre0, bih0, bhh0, H_, E_);

  // 4) recurrence, layers software-pipelined across 513 launches
  for (int t = 0; t <= T_; ++t)
    k_rnn_step<<<128, 256, 0, stream>>>(t, pre0, whh0_bf, wih1_bf, whh1_bf,
                                        bih1, bhh1, y0, y1, hid);

  // 5) logits = y1 @ fc_w^T + fc_b   [8192,32000]
  dim3 g2(V_ / 128, (B_ * T_) / 128);
  k_gemm_bt<<<g2, 256, 0, stream>>>(y1, fcw_bf, out, fcb, nullptr, V_, H_);
}